// Round 8
// baseline (384.567 us; speedup 1.0000x reference)
//
#include <hip/hip_runtime.h>
#include <math.h>

#define BB    4
#define TT    1024
#define EE    1024
#define HH    16
#define HDIM  64
#define SS    2048
#define MROWS 4096
#define SCALEQ 0.125f

typedef short  s8v  __attribute__((ext_vector_type(8)));
typedef float  f4v  __attribute__((ext_vector_type(4)));

__device__ __forceinline__ unsigned short f2bf(float f) {
    union { float f; unsigned u; } c; c.f = f;
    unsigned u = c.u + 0x7FFFu + ((c.u >> 16) & 1u);
    return (unsigned short)(u >> 16);
}
__device__ __forceinline__ float bf2f(unsigned short h) {
    union { unsigned u; float f; } c; c.u = ((unsigned)h) << 16;
    return c.f;
}

__device__ __forceinline__ void async16(const void* g, void* l) {
    __builtin_amdgcn_global_load_lds(
        (const __attribute__((address_space(1))) unsigned int*)g,
        (__attribute__((address_space(3))) unsigned int*)l,
        16, 0, 0);
}

// ---------------------------------------------------------------------------
// Fused fp32->bf16 convert: x, Wq, Wk, Wv, Wo, mask.
// ---------------------------------------------------------------------------
__global__ __launch_bounds__(256) void cvt6_kernel(
    const float* __restrict__ x,  const float* __restrict__ wq,
    const float* __restrict__ wk, const float* __restrict__ wv,
    const float* __restrict__ wo, const float* __restrict__ mk,
    unsigned short* __restrict__ xb,  unsigned short* __restrict__ wqb,
    unsigned short* __restrict__ wkb, unsigned short* __restrict__ wvb,
    unsigned short* __restrict__ wob, unsigned short* __restrict__ mbb)
{
    const int total = 3670016;
    int i = blockIdx.x * 256 + threadIdx.x;
    const int stride = gridDim.x * 256;
    for (; i < total; i += stride) {
        const float* s; unsigned short* d; int off;
        if (i < 1048576)      { s = x;  d = xb;  off = i; }
        else if (i < 1310720) { s = wq; d = wqb; off = i - 1048576; }
        else if (i < 1835008) { s = wk; d = wkb; off = i - 1310720; }
        else if (i < 2359296) { s = wv; d = wvb; off = i - 1835008; }
        else if (i < 2621440) { s = wo; d = wob; off = i - 2359296; }
        else                  { s = mk; d = mbb; off = i - 2621440; }
        float4 v = ((const float4*)s)[off];
        ushort4 o;
        o.x = f2bf(v.x); o.y = f2bf(v.y); o.z = f2bf(v.z); o.w = f2bf(v.w);
        ((ushort4*)d)[off] = o;
    }
}

// ---------------------------------------------------------------------------
#define GEMM_KLOOP(Aptr, Wptr, Ksz)                                            \
    for (int k0 = 0; k0 < (Ksz); k0 += 32) {                                   \
        _Pragma("unroll")                                                      \
        for (int it = 0; it < 2; ++it) {                                       \
            int f = (it * 4 + w) * 64 + lane;                                  \
            int r = f >> 2, g = (f & 3) * 8;                                   \
            async16((Aptr) + (size_t)r * (Ksz) + k0 + g,                       \
                    As + (it * 4 + w) * 512);                                  \
            async16((Wptr) + (size_t)r * (Ksz) + k0 + g,                       \
                    Bs + (it * 4 + w) * 512);                                  \
        }                                                                      \
        __syncthreads();                                                       \
        s8v af[4], bf[4];                                                      \
        _Pragma("unroll")                                                      \
        for (int i = 0; i < 4; ++i)                                            \
            af[i] = *(const s8v*)(As + (wm + i * 16 + col16) * 32 + quad * 8); \
        _Pragma("unroll")                                                      \
        for (int j = 0; j < 4; ++j)                                            \
            bf[j] = *(const s8v*)(Bs + (wn + j * 16 + col16) * 32 + quad * 8); \
        _Pragma("unroll")                                                      \
        for (int i = 0; i < 4; ++i)                                            \
            _Pragma("unroll")                                                  \
            for (int j = 0; j < 4; ++j)                                        \
                acc[i][j] = __builtin_amdgcn_mfma_f32_16x16x32_bf16(           \
                    af[i], bf[j], acc[i][j], 0, 0, 0);                         \
        __syncthreads();                                                       \
    }

// ---------------------------------------------------------------------------
// Fused Q+K+V projection (unchanged from R7; passed, ~same time as split).
// ---------------------------------------------------------------------------
__global__ __launch_bounds__(256, 4) void gemm_qkv_kernel(
    const unsigned short* __restrict__ X,
    const unsigned short* __restrict__ Wq, const unsigned short* __restrict__ Wk,
    const unsigned short* __restrict__ Wv,
    const float* __restrict__ bq, const float* __restrict__ bk,
    const float* __restrict__ bv,
    unsigned short* __restrict__ qp, unsigned short* __restrict__ kp,
    unsigned short* __restrict__ vt)
{
    __shared__ __align__(16) unsigned short As[128 * 32];
    __shared__ __align__(16) unsigned short Bs[128 * 32];

    const int tid = threadIdx.x;
    const int lane = tid & 63, w = tid >> 6;
    const int wm = (w & 1) * 64, wn = (w >> 1) * 64;
    const int col16 = lane & 15, quad = lane >> 4;

    const int gid = blockIdx.x;
    int mode, mi, ni;
    const unsigned short *Ab, *Bb;
    if (gid < 256) {
        mode = 0; mi = gid >> 3; ni = gid & 7;
        Ab = X + (size_t)mi * 128 * EE;  Bb = Wq + (size_t)ni * 128 * EE;
    } else if (gid < 768) {
        int g = gid - 256; mode = 1; mi = g >> 4; ni = g & 15;
        Ab = X + (size_t)mi * 128 * EE;  Bb = Wk + (size_t)ni * 128 * EE;
    } else {
        int g = gid - 768; mode = 2; mi = g & 15; ni = g >> 4;
        Ab = Wv + (size_t)mi * 128 * EE; Bb = X + (size_t)ni * 128 * EE;
    }

    f4v acc[4][4];
#pragma unroll
    for (int i = 0; i < 4; ++i)
#pragma unroll
        for (int j = 0; j < 4; ++j) acc[i][j] = (f4v)0.0f;

    GEMM_KLOOP(Ab, Bb, EE)

#pragma unroll
    for (int j = 0; j < 4; ++j) {
        const int nl = wn + j * 16 + col16;
#pragma unroll
        for (int i = 0; i < 4; ++i) {
#pragma unroll
            for (int r = 0; r < 4; ++r) {
                const int ml = wm + i * 16 + quad * 4 + r;
                float c = acc[i][j][r];
                if (mode == 0) {
                    const int m = mi * 128 + ml, n = ni * 128 + nl;
                    qp[(size_t)m * EE + n] = f2bf((c + bq[n]) * SCALEQ);
                } else if (mode == 1) {
                    const int m = mi * 128 + ml, nk = ni * 128 + nl;
                    const int mm = nk >> 10, h = (nk >> 6) & 15, d = nk & 63;
                    const int b_ = m >> 10, t = m & 1023;
                    const int s = 2 * t + mm;
                    kp[((size_t)(b_ * HH + h) * SS + s) * HDIM + d] = f2bf(c + bk[nk]);
                } else {
                    const int f = mi * 128 + ml, tok = ni * 128 + nl;
                    const int mm = f >> 10, h = (f >> 6) & 15, d = f & 63;
                    const int b_ = tok >> 10, t = tok & 1023;
                    const int s = 2 * t + mm;
                    vt[((size_t)(b_ * HH + h) * HDIM + d) * SS + s] = f2bf(c + bv[f]);
                }
            }
        }
    }
}

// ---------------------------------------------------------------------------
// O-projection GEMM, 64x128 tile -> 512 blocks (2/CU). fp32 out.
// ---------------------------------------------------------------------------
__global__ __launch_bounds__(256, 4) void gemm_o64_kernel(
    const unsigned short* __restrict__ A, const unsigned short* __restrict__ W,
    const float* __restrict__ bias, float* __restrict__ Cout)
{
    __shared__ __align__(16) unsigned short As[64 * 32];
    __shared__ __align__(16) unsigned short Bs[128 * 32];

    const int tid = threadIdx.x;
    const int lane = tid & 63, w = tid >> 6;
    const int col16 = lane & 15, quad = lane >> 4;
    const int m0 = blockIdx.x * 64;
    const int n0 = blockIdx.y * 128;
    const unsigned short* Ab = A + (size_t)m0 * EE;
    const unsigned short* Bb = W + (size_t)n0 * EE;

    f4v acc[4][2];
#pragma unroll
    for (int i = 0; i < 4; ++i)
#pragma unroll
        for (int j = 0; j < 2; ++j) acc[i][j] = (f4v)0.0f;

    for (int k0 = 0; k0 < EE; k0 += 32) {
        {   // A: 1 chunk/thread; dest uniform base + lane*16
            int r = tid >> 2, g = (tid & 3) * 8;
            async16(Ab + (size_t)r * EE + k0 + g, As + w * 512);
        }
#pragma unroll
        for (int it = 0; it < 2; ++it) {  // B: 2 chunks/thread
            int f = (it * 4 + w) * 64 + lane;
            int r = f >> 2, g = (f & 3) * 8;
            async16(Bb + (size_t)r * EE + k0 + g, Bs + (it * 4 + w) * 512);
        }
        __syncthreads();
        s8v af[4], bf[2];
#pragma unroll
        for (int i = 0; i < 4; ++i)
            af[i] = *(const s8v*)(As + (i * 16 + col16) * 32 + quad * 8);
#pragma unroll
        for (int j = 0; j < 2; ++j)
            bf[j] = *(const s8v*)(Bs + (w * 32 + j * 16 + col16) * 32 + quad * 8);
#pragma unroll
        for (int i = 0; i < 4; ++i)
#pragma unroll
            for (int j = 0; j < 2; ++j)
                acc[i][j] = __builtin_amdgcn_mfma_f32_16x16x32_bf16(
                    af[i], bf[j], acc[i][j], 0, 0, 0);
        __syncthreads();
    }

#pragma unroll
    for (int j = 0; j < 2; ++j) {
        const int n = n0 + w * 32 + j * 16 + col16;
        const float bn = bias[n];
#pragma unroll
        for (int i = 0; i < 4; ++i)
#pragma unroll
            for (int r = 0; r < 4; ++r) {
                const int m = m0 + i * 16 + quad * 4 + r;
                Cout[(size_t)m * EE + n] = acc[i][j][r] + bn;
            }
    }
}

// ---------------------------------------------------------------------------
// Flash attention v5: R5 structure, 2 barriers/iter.
//  - S^T = K.Q^T (Q frags in regs): C col = t = w*16+col16 (per-lane t)
//  - softmax in-reg (2 shfls), per-lane scl
//  - P transpose C-layout -> B-operand layout via ds_bpermute (no LDS, no
//    barriers): for (ks,dw): src_lane = ((quad&1)*2+(dw>>1))*16+col16,
//    js = 2ks + (quad>=2), dword = dw&1  [verified on 5 concrete cases]
//  - O^T += V^T.P^T (A=V from LDS, B=P from regs): C col = t -> per-lane
//    rescale/normalize (R6-validated formulation)
//  - mask: direct bf16 global gathers (4x8B/iter, L2-resident via XCD swizzle),
//    issued before QK so MFMA covers latency
// LDS = K0|K1|V0|V1 = 34.8 KB -> 4 blocks/CU; grid 1024 = 4x256 exact.
// ---------------------------------------------------------------------------
__global__ __launch_bounds__(256, 4) void attn_mfma5_kernel(
    const unsigned short* __restrict__ Q, const unsigned short* __restrict__ Kh,
    const unsigned short* __restrict__ Vt, const unsigned short* __restrict__ Mb,
    unsigned short* __restrict__ O)
{
    constexpr int PT = 68;   // 136B pitch (R5: 0 bank conflicts)
    __shared__ __align__(16) unsigned short K0[64 * PT];
    __shared__ __align__(16) unsigned short K1[64 * PT];
    __shared__ __align__(16) unsigned short V0s[64 * PT];
    __shared__ __align__(16) unsigned short V1s[64 * PT];

    const int tid = threadIdx.x;
    const int lane = tid & 63, w = tid >> 6;
    const int col16 = lane & 15, quad = lane >> 4;
    const bool lowq = quad < 2;
    // bpermute source-lane byte addresses (dw>>1 = 0 / 1)
    const int addr0 = (((quad & 1) * 2 + 0) * 16 + col16) * 4;
    const int addr1 = (((quad & 1) * 2 + 1) * 16 + col16) * 4;

    // XCD swizzle (as R5)
    const int gid = blockIdx.x;
    const int v = gid & 7, j = gid >> 3;
    const int bh = v * 8 + (j >> 4);
    const int t0 = (j & 15) * 64;
    const int b_ = bh >> 4, h = bh & 15;

    const unsigned short* Kb  = Kh + (size_t)bh * SS * HDIM;
    const unsigned short* Vb  = Vt + (size_t)bh * HDIM * SS;
    const unsigned short* Mrow = Mb + (size_t)b_ * TT * TT
                                  + (size_t)(t0 + w * 16 + col16) * TT;

    // Q B-frags in registers (lane's t-row = w*16+col16) [R7-proven]
    const unsigned short* Qrow = Q + (size_t)(b_ * TT + t0 + w * 16 + col16) * EE + h * HDIM;
    s8v qf[2];
    qf[0] = *(const s8v*)(Qrow + quad * 8);
    qf[1] = *(const s8v*)(Qrow + 32 + quad * 8);

    f4v oacc[4];
#pragma unroll
    for (int jd = 0; jd < 4; ++jd) oacc[jd] = (f4v)0.0f;
    float mrun = -INFINITY, lrun = 0.0f;

    for (int it16 = 0; it16 < 16; ++it16) {
        const int t2b = it16 * 64;
        __syncthreads();  // (A) prev iter's K (QK) and V (PV) LDS reads done
#pragma unroll
        for (int st = 0; st < 2; ++st) {
            int idx = tid + st * 256;
            int r = idx >> 3, c = (idx & 7) * 8;
            *(uint4*)(K0 + r * PT + c)  = *(const uint4*)(Kb + (size_t)(t2b + r) * HDIM + c);
            *(uint4*)(K1 + r * PT + c)  = *(const uint4*)(Kb + (size_t)(1024 + t2b + r) * HDIM + c);
            *(uint4*)(V0s + r * PT + c) = *(const uint4*)(Vb + (size_t)r * SS + t2b + c);
            *(uint4*)(V1s + r * PT + c) = *(const uint4*)(Vb + (size_t)r * SS + 1024 + t2b + c);
        }
        __syncthreads();  // (B)

        // mask gathers issued first (independent of LDS) — latency hides under QK
        uint2 mu[4];
#pragma unroll
        for (int js = 0; js < 4; ++js)
            mu[js] = *(const uint2*)(Mrow + t2b + js * 16 + quad * 4);

        // S^T halves: A=K (m=s), B=Q (n=t)
        f4v s0acc[4], s1acc[4];
#pragma unroll
        for (int js = 0; js < 4; ++js) { s0acc[js] = (f4v)0.0f; s1acc[js] = (f4v)0.0f; }
#pragma unroll
        for (int ks = 0; ks < 2; ++ks) {
            s8v bq_ = qf[ks];
#pragma unroll
            for (int js = 0; js < 4; ++js) {
                s8v ak0 = *(const s8v*)(K0 + (js * 16 + col16) * PT + ks * 32 + quad * 8);
                s8v ak1 = *(const s8v*)(K1 + (js * 16 + col16) * PT + ks * 32 + quad * 8);
                s0acc[js] = __builtin_amdgcn_mfma_f32_16x16x32_bf16(ak0, bq_, s0acc[js], 0, 0, 0);
                s1acc[js] = __builtin_amdgcn_mfma_f32_16x16x32_bf16(ak1, bq_, s1acc[js], 0, 0, 0);
            }
        }

        // mask add: C element (s-row = js*16+quad*4+r, t-col); same cols both halves
#pragma unroll
        for (int js = 0; js < 4; ++js) {
            float m0f = bf2f((unsigned short)(mu[js].x & 0xffff));
            float m1f = bf2f((unsigned short)(mu[js].x >> 16));
            float m2f = bf2f((unsigned short)(mu[js].y & 0xffff));
            float m3f = bf2f((unsigned short)(mu[js].y >> 16));
            s0acc[js][0] += m0f; s1acc[js][0] += m0f;
            s0acc[js][1] += m1f; s1acc[js][1] += m1f;
            s0acc[js][2] += m2f; s1acc[js][2] += m2f;
            s0acc[js][3] += m3f; s1acc[js][3] += m3f;
        }

        // online softmax over 128 s for this lane's t (4 quads share t)
        float tmax = -INFINITY;
#pragma unroll
        for (int js = 0; js < 4; ++js)
#pragma unroll
            for (int r = 0; r < 4; ++r)
                tmax = fmaxf(tmax, fmaxf(s0acc[js][r], s1acc[js][r]));
        tmax = fmaxf(tmax, __shfl_xor(tmax, 16));
        tmax = fmaxf(tmax, __shfl_xor(tmax, 32));
        const float mnew = fmaxf(mrun, tmax);
        const float scl = __expf(mrun - mnew);   // 0 on first tile
        float rs = 0.0f;
#pragma unroll
        for (int js = 0; js < 4; ++js)
#pragma unroll
            for (int r = 0; r < 4; ++r) {
                float p0 = __expf(s0acc[js][r] - mnew);
                float p1 = __expf(s1acc[js][r] - mnew);
                s0acc[js][r] = p0; s1acc[js][r] = p1;
                rs += p0 + p1;
            }
        rs += __shfl_xor(rs, 16);
        rs += __shfl_xor(rs, 32);
        lrun = lrun * scl + rs;
        mrun = mnew;

        // O^T rescale: C col = t = col16 -> purely per-lane
#pragma unroll
        for (int jd = 0; jd < 4; ++jd) oacc[jd] *= scl;

        // pack P (bf16 pairs): pk[half][js] = {s0|s1, s2|s3} at lane (quad_s, t)
        uint2 pk0[4], pk1[4];
#pragma unroll
        for (int js = 0; js < 4; ++js) {
            pk0[js].x = (unsigned)f2bf(s0acc[js][0]) | ((unsigned)f2bf(s0acc[js][1]) << 16);
            pk0[js].y = (unsigned)f2bf(s0acc[js][2]) | ((unsigned)f2bf(s0acc[js][3]) << 16);
            pk1[js].x = (unsigned)f2bf(s1acc[js][0]) | ((unsigned)f2bf(s1acc[js][1]) << 16);
            pk1[js].y = (unsigned)f2bf(s1acc[js][2]) | ((unsigned)f2bf(s1acc[js][3]) << 16);
        }

        // O^T += V^T . P^T per half: A=V (LDS), B=P^T (bpermute, no barrier)
#pragma unroll
        for (int hh = 0; hh < 2; ++hh) {
            const uint2* pk = hh ? pk1 : pk0;
            const unsigned short* Vs = hh ? V1s : V0s;
#pragma unroll
            for (int ks = 0; ks < 2; ++ks) {
                const uint2 A2 = pk[ks * 2];
                const uint2 B2 = pk[ks * 2 + 1];
                int r0a = __builtin_amdgcn_ds_bpermute(addr0, (int)A2.x);
                int r0b = __builtin_amdgcn_ds_bpermute(addr0, (int)B2.x);
                int r1a = __builtin_amdgcn_ds_bpermute(addr0, (int)A2.y);
                int r1b = __builtin_amdgcn_ds_bpermute(addr0, (int)B2.y);
                int r2a = __builtin_amdgcn_ds_bpermute(addr1, (int)A2.x);
                int r2b = __builtin_amdgcn_ds_bpermute(addr1, (int)B2.x);
                int r3a = __builtin_amdgcn_ds_bpermute(addr1, (int)A2.y);
                int r3b = __builtin_amdgcn_ds_bpermute(addr1, (int)B2.y);
                union { int i[4]; s8v v; } pf;
                pf.i[0] = lowq ? r0a : r0b;
                pf.i[1] = lowq ? r1a : r1b;
                pf.i[2] = lowq ? r2a : r2b;
                pf.i[3] = lowq ? r3a : r3b;
#pragma unroll
                for (int jd = 0; jd < 4; ++jd) {
                    s8v vf = *(const s8v*)(Vs + (jd * 16 + col16) * PT + ks * 32 + quad * 8);
                    oacc[jd] = __builtin_amdgcn_mfma_f32_16x16x32_bf16(vf, pf.v, oacc[jd], 0, 0, 0);
                }
            }
        }
    }

    // epilogue: O^T element (d = jd*16+quad*4+r, t = col16) -> O[t][h*64+d]
    const float inv = 1.0f / lrun;
    const int tg = b_ * TT + t0 + w * 16 + col16;
#pragma unroll
    for (int jd = 0; jd < 4; ++jd) {
        unsigned lo = (unsigned)f2bf(oacc[jd][0] * inv) |
                      ((unsigned)f2bf(oacc[jd][1] * inv) << 16);
        unsigned hi = (unsigned)f2bf(oacc[jd][2] * inv) |
                      ((unsigned)f2bf(oacc[jd][3] * inv) << 16);
        *(uint2*)(O + (size_t)tg * EE + h * HDIM + jd * 16 + quad * 4) =
            make_uint2(lo, hi);
    }
}

// ---------------------------------------------------------------------------
extern "C" void kernel_launch(void* const* d_in, const int* in_sizes, int n_in,
                              void* d_out, int out_size, void* d_ws, size_t ws_size,
                              hipStream_t stream)
{
    (void)in_sizes; (void)n_in; (void)out_size; (void)ws_size;

    const float* x    = (const float*)d_in[0];
    const float* mask = (const float*)d_in[1];
    const float* Wq   = (const float*)d_in[2];
    const float* bq   = (const float*)d_in[3];
    const float* Wk   = (const float*)d_in[4];
    const float* bk   = (const float*)d_in[5];
    const float* Wv   = (const float*)d_in[6];
    const float* bv   = (const float*)d_in[7];
    const float* Wo   = (const float*)d_in[8];
    const float* bo   = (const float*)d_in[9];
    float* out = (float*)d_out;

    unsigned short* xb  = (unsigned short*)d_ws;
    unsigned short* wqb = xb  + (size_t)MROWS * EE;
    unsigned short* wkb = wqb + (size_t)EE * EE;
    unsigned short* wvb = wkb + (size_t)2 * EE * EE;
    unsigned short* wob = wvb + (size_t)2 * EE * EE;
    unsigned short* mb  = wob + (size_t)EE * EE;
    unsigned short* qp  = mb  + (size_t)BB * TT * TT;
    unsigned short* kp  = qp  + (size_t)MROWS * EE;
    unsigned short* vt  = kp  + (size_t)BB * HH * SS * HDIM;
    unsigned short* ao  = vt  + (size_t)BB * HH * SS * HDIM;

    dim3 blk(256);

    cvt6_kernel<<<4096, blk, 0, stream>>>(x, Wq, Wk, Wv, Wo, mask,
                                          xb, wqb, wkb, wvb, wob, mb);
    gemm_qkv_kernel<<<dim3(1280), blk, 0, stream>>>(
        xb, wqb, wkb, wvb, bq, bk, bv, qp, kp, vt);
    attn_mfma5_kernel<<<dim3(1024), blk, 0, stream>>>(qp, kp, vt, mb, ao);
    gemm_o64_kernel<<<dim3(64, 8), blk, 0, stream>>>(ao, wob, bo, out);
}

// Round 9
// 303.121 us; speedup vs baseline: 1.2687x; 1.2687x over previous
//
#include <hip/hip_runtime.h>
#include <math.h>

#define BB    4
#define TT    1024
#define EE    1024
#define HH    16
#define HDIM  64
#define SS    2048
#define MROWS 4096
#define SCALEQ 0.125f

typedef short  s8v  __attribute__((ext_vector_type(8)));
typedef float  f4v  __attribute__((ext_vector_type(4)));

__device__ __forceinline__ unsigned short f2bf(float f) {
    union { float f; unsigned u; } c; c.f = f;
    unsigned u = c.u + 0x7FFFu + ((c.u >> 16) & 1u);
    return (unsigned short)(u >> 16);
}
__device__ __forceinline__ float bf2f(unsigned short h) {
    union { unsigned u; float f; } c; c.u = ((unsigned)h) << 16;
    return c.f;
}

__device__ __forceinline__ void async16(const void* g, void* l) {
    __builtin_amdgcn_global_load_lds(
        (const __attribute__((address_space(1))) unsigned int*)g,
        (__attribute__((address_space(3))) unsigned int*)l,
        16, 0, 0);
}

// ---------------------------------------------------------------------------
// Fused fp32->bf16 convert: x, Wq, Wk, Wv, Wo, mask. (verified R5-R8)
// ---------------------------------------------------------------------------
__global__ __launch_bounds__(256) void cvt6_kernel(
    const float* __restrict__ x,  const float* __restrict__ wq,
    const float* __restrict__ wk, const float* __restrict__ wv,
    const float* __restrict__ wo, const float* __restrict__ mk,
    unsigned short* __restrict__ xb,  unsigned short* __restrict__ wqb,
    unsigned short* __restrict__ wkb, unsigned short* __restrict__ wvb,
    unsigned short* __restrict__ wob, unsigned short* __restrict__ mbb)
{
    const int total = 3670016;
    int i = blockIdx.x * 256 + threadIdx.x;
    const int stride = gridDim.x * 256;
    for (; i < total; i += stride) {
        const float* s; unsigned short* d; int off;
        if (i < 1048576)      { s = x;  d = xb;  off = i; }
        else if (i < 1310720) { s = wq; d = wqb; off = i - 1048576; }
        else if (i < 1835008) { s = wk; d = wkb; off = i - 1310720; }
        else if (i < 2359296) { s = wv; d = wvb; off = i - 1835008; }
        else if (i < 2621440) { s = wo; d = wob; off = i - 2359296; }
        else                  { s = mk; d = mbb; off = i - 2621440; }
        float4 v = ((const float4*)s)[off];
        ushort4 o;
        o.x = f2bf(v.x); o.y = f2bf(v.y); o.z = f2bf(v.z); o.w = f2bf(v.w);
        ((ushort4*)d)[off] = o;
    }
}

// ---------------------------------------------------------------------------
#define GEMM_KLOOP(Aptr, Wptr, Ksz)                                            \
    for (int k0 = 0; k0 < (Ksz); k0 += 32) {                                   \
        _Pragma("unroll")                                                      \
        for (int it = 0; it < 2; ++it) {                                       \
            int f = (it * 4 + w) * 64 + lane;                                  \
            int r = f >> 2, g = (f & 3) * 8;                                   \
            async16((Aptr) + (size_t)r * (Ksz) + k0 + g,                       \
                    As + (it * 4 + w) * 512);                                  \
            async16((Wptr) + (size_t)r * (Ksz) + k0 + g,                       \
                    Bs + (it * 4 + w) * 512);                                  \
        }                                                                      \
        __syncthreads();                                                       \
        s8v af[4], bf[4];                                                      \
        _Pragma("unroll")                                                      \
        for (int i = 0; i < 4; ++i)                                            \
            af[i] = *(const s8v*)(As + (wm + i * 16 + col16) * 32 + quad * 8); \
        _Pragma("unroll")                                                      \
        for (int j = 0; j < 4; ++j)                                            \
            bf[j] = *(const s8v*)(Bs + (wn + j * 16 + col16) * 32 + quad * 8); \
        _Pragma("unroll")                                                      \
        for (int i = 0; i < 4; ++i)                                            \
            _Pragma("unroll")                                                  \
            for (int j = 0; j < 4; ++j)                                        \
                acc[i][j] = __builtin_amdgcn_mfma_f32_16x16x32_bf16(           \
                    af[i], bf[j], acc[i][j], 0, 0, 0);                         \
        __syncthreads();                                                       \
    }

// ---------------------------------------------------------------------------
// Fused Q+K+V projection (verified R7/R8).
// ---------------------------------------------------------------------------
__global__ __launch_bounds__(256, 4) void gemm_qkv_kernel(
    const unsigned short* __restrict__ X,
    const unsigned short* __restrict__ Wq, const unsigned short* __restrict__ Wk,
    const unsigned short* __restrict__ Wv,
    const float* __restrict__ bq, const float* __restrict__ bk,
    const float* __restrict__ bv,
    unsigned short* __restrict__ qp, unsigned short* __restrict__ kp,
    unsigned short* __restrict__ vt)
{
    __shared__ __align__(16) unsigned short As[128 * 32];
    __shared__ __align__(16) unsigned short Bs[128 * 32];

    const int tid = threadIdx.x;
    const int lane = tid & 63, w = tid >> 6;
    const int wm = (w & 1) * 64, wn = (w >> 1) * 64;
    const int col16 = lane & 15, quad = lane >> 4;

    const int gid = blockIdx.x;
    int mode, mi, ni;
    const unsigned short *Ab, *Bb;
    if (gid < 256) {
        mode = 0; mi = gid >> 3; ni = gid & 7;
        Ab = X + (size_t)mi * 128 * EE;  Bb = Wq + (size_t)ni * 128 * EE;
    } else if (gid < 768) {
        int g = gid - 256; mode = 1; mi = g >> 4; ni = g & 15;
        Ab = X + (size_t)mi * 128 * EE;  Bb = Wk + (size_t)ni * 128 * EE;
    } else {
        int g = gid - 768; mode = 2; mi = g & 15; ni = g >> 4;
        Ab = Wv + (size_t)mi * 128 * EE; Bb = X + (size_t)ni * 128 * EE;
    }

    f4v acc[4][4];
#pragma unroll
    for (int i = 0; i < 4; ++i)
#pragma unroll
        for (int j = 0; j < 4; ++j) acc[i][j] = (f4v)0.0f;

    GEMM_KLOOP(Ab, Bb, EE)

#pragma unroll
    for (int j = 0; j < 4; ++j) {
        const int nl = wn + j * 16 + col16;
#pragma unroll
        for (int i = 0; i < 4; ++i) {
#pragma unroll
            for (int r = 0; r < 4; ++r) {
                const int ml = wm + i * 16 + quad * 4 + r;
                float c = acc[i][j][r];
                if (mode == 0) {
                    const int m = mi * 128 + ml, n = ni * 128 + nl;
                    qp[(size_t)m * EE + n] = f2bf((c + bq[n]) * SCALEQ);
                } else if (mode == 1) {
                    const int m = mi * 128 + ml, nk = ni * 128 + nl;
                    const int mm = nk >> 10, h = (nk >> 6) & 15, d = nk & 63;
                    const int b_ = m >> 10, t = m & 1023;
                    const int s = 2 * t + mm;
                    kp[((size_t)(b_ * HH + h) * SS + s) * HDIM + d] = f2bf(c + bk[nk]);
                } else {
                    const int f = mi * 128 + ml, tok = ni * 128 + nl;
                    const int mm = f >> 10, h = (f >> 6) & 15, d = f & 63;
                    const int b_ = tok >> 10, t = tok & 1023;
                    const int s = 2 * t + mm;
                    vt[((size_t)(b_ * HH + h) * HDIM + d) * SS + s] = f2bf(c + bv[f]);
                }
            }
        }
    }
}

// ---------------------------------------------------------------------------
// O-projection GEMM, 64x128 tile -> 512 blocks (verified R8).
// ---------------------------------------------------------------------------
__global__ __launch_bounds__(256, 4) void gemm_o64_kernel(
    const unsigned short* __restrict__ A, const unsigned short* __restrict__ W,
    const float* __restrict__ bias, float* __restrict__ Cout)
{
    __shared__ __align__(16) unsigned short As[64 * 32];
    __shared__ __align__(16) unsigned short Bs[128 * 32];

    const int tid = threadIdx.x;
    const int lane = tid & 63, w = tid >> 6;
    const int col16 = lane & 15, quad = lane >> 4;
    const int m0 = blockIdx.x * 64;
    const int n0 = blockIdx.y * 128;
    const unsigned short* Ab = A + (size_t)m0 * EE;
    const unsigned short* Bb = W + (size_t)n0 * EE;

    f4v acc[4][2];
#pragma unroll
    for (int i = 0; i < 4; ++i)
#pragma unroll
        for (int j = 0; j < 2; ++j) acc[i][j] = (f4v)0.0f;

    for (int k0 = 0; k0 < EE; k0 += 32) {
        {
            int r = tid >> 2, g = (tid & 3) * 8;
            async16(Ab + (size_t)r * EE + k0 + g, As + w * 512);
        }
#pragma unroll
        for (int it = 0; it < 2; ++it) {
            int f = (it * 4 + w) * 64 + lane;
            int r = f >> 2, g = (f & 3) * 8;
            async16(Bb + (size_t)r * EE + k0 + g, Bs + (it * 4 + w) * 512);
        }
        __syncthreads();
        s8v af[4], bf[2];
#pragma unroll
        for (int i = 0; i < 4; ++i)
            af[i] = *(const s8v*)(As + (i * 16 + col16) * 32 + quad * 8);
#pragma unroll
        for (int j = 0; j < 2; ++j)
            bf[j] = *(const s8v*)(Bs + (w * 32 + j * 16 + col16) * 32 + quad * 8);
#pragma unroll
        for (int i = 0; i < 4; ++i)
#pragma unroll
            for (int j = 0; j < 2; ++j)
                acc[i][j] = __builtin_amdgcn_mfma_f32_16x16x32_bf16(
                    af[i], bf[j], acc[i][j], 0, 0, 0);
        __syncthreads();
    }

#pragma unroll
    for (int j = 0; j < 2; ++j) {
        const int n = n0 + w * 32 + j * 16 + col16;
        const float bn = bias[n];
#pragma unroll
        for (int i = 0; i < 4; ++i)
#pragma unroll
            for (int r = 0; r < 4; ++r) {
                const int m = m0 + i * 16 + quad * 4 + r;
                Cout[(size_t)m * EE + n] = acc[i][j][r] + bn;
            }
    }
}

// ---------------------------------------------------------------------------
// Flash attention v6: R5 verified semantics, restructured for occupancy.
//  - single 64-s tile per iter (32 iters), t2b = s0 & 1023
//  - LDS = Ks | Vs | Ms | Ps = 34 KB -> 4 blocks/CU; grid 1024 fully resident
//  - P is WAVE-PRIVATE (wave w only touches t-rows w*16+col16): dedicated Ps
//    buffer -> no barrier between P write and P read (in-wave lgkmcnt order;
//    per-lane write/read addresses alias so the compiler must emit the wait)
//  - 2 barriers/iter: (A) guard restaging of Ks/Vs/Ms, (B) staging visible
//  - Q frags in regs (R7/R8-verified); mask staged coalesced in LDS (R5 rule)
// ---------------------------------------------------------------------------
__global__ __launch_bounds__(256, 4) void attn_mfma6_kernel(
    const unsigned short* __restrict__ Q, const unsigned short* __restrict__ Kh,
    const unsigned short* __restrict__ Vt, const unsigned short* __restrict__ Mb,
    unsigned short* __restrict__ O)
{
    constexpr int PT = 68;   // 136B pitch (R5-proven: 0 bank conflicts)
    __shared__ __align__(16) unsigned short Ks[64 * PT];
    __shared__ __align__(16) unsigned short Vs[64 * PT];  // V^T tile [d][s]
    __shared__ __align__(16) unsigned short Ms[64 * PT];  // mask [t][t2] bf16
    __shared__ __align__(16) unsigned short Ps[64 * PT];  // P [t][s], wave-private rows

    const int tid = threadIdx.x;
    const int lane = tid & 63, w = tid >> 6;
    const int col16 = lane & 15, quad = lane >> 4;

    // XCD swizzle (R5): 8 consecutive bh per virtual XCD
    const int gid = blockIdx.x;
    const int v = gid & 7, j = gid >> 3;
    const int bh = v * 8 + (j >> 4);
    const int t0 = (j & 15) * 64;
    const int b_ = bh >> 4, h = bh & 15;

    const unsigned short* Kb  = Kh + (size_t)bh * SS * HDIM;
    const unsigned short* Vb  = Vt + (size_t)bh * HDIM * SS;
    const unsigned short* Mbb = Mb + (size_t)b_ * TT * TT;
    const int myrow = (w * 16 + col16) * PT;

    // Q B-frags in registers (lane's t-row = w*16+col16)
    const unsigned short* Qrow = Q + (size_t)(b_ * TT + t0 + w * 16 + col16) * EE + h * HDIM;
    s8v qf[2];
    qf[0] = *(const s8v*)(Qrow + quad * 8);
    qf[1] = *(const s8v*)(Qrow + 32 + quad * 8);

    f4v oacc[4];
#pragma unroll
    for (int jd = 0; jd < 4; ++jd) oacc[jd] = (f4v)0.0f;
    float mrun = -INFINITY, lrun = 0.0f;

    for (int s0 = 0; s0 < SS; s0 += 64) {
        const int t2b = s0 & (TT - 1);
        __syncthreads();  // (A) prev iter's Ks/Vs/Ms reads done
#pragma unroll
        for (int st = 0; st < 2; ++st) {
            int idx = tid + st * 256;
            int r = idx >> 3, c = (idx & 7) * 8;
            *(uint4*)(Ks + r * PT + c) = *(const uint4*)(Kb + (size_t)(s0 + r) * HDIM + c);
            *(uint4*)(Vs + r * PT + c) = *(const uint4*)(Vb + (size_t)r * SS + s0 + c);
            *(uint4*)(Ms + r * PT + c) = *(const uint4*)(Mbb + (size_t)(t0 + r) * TT + t2b + c);
        }
        __syncthreads();  // (B)

        // S^T = K.Q^T : A=K (m=s), B=Q (n=t); C col = t (per-lane col16)
        f4v sacc[4];
#pragma unroll
        for (int js = 0; js < 4; ++js) sacc[js] = (f4v)0.0f;
#pragma unroll
        for (int ks = 0; ks < 2; ++ks) {
            s8v bq_ = qf[ks];
#pragma unroll
            for (int js = 0; js < 4; ++js) {
                s8v ak = *(const s8v*)(Ks + (js * 16 + col16) * PT + ks * 32 + quad * 8);
                sacc[js] = __builtin_amdgcn_mfma_f32_16x16x32_bf16(ak, bq_, sacc[js], 0, 0, 0);
            }
        }

        // mask add from LDS (R5-verified indices): s-row = js*16+quad*4+r
#pragma unroll
        for (int js = 0; js < 4; ++js) {
            uint2 mm = *(const uint2*)(Ms + myrow + js * 16 + quad * 4);
            sacc[js][0] += bf2f((unsigned short)(mm.x & 0xffff));
            sacc[js][1] += bf2f((unsigned short)(mm.x >> 16));
            sacc[js][2] += bf2f((unsigned short)(mm.y & 0xffff));
            sacc[js][3] += bf2f((unsigned short)(mm.y >> 16));
        }

        // online softmax over 64 s for this lane's t (4 quads share t)
        float tmax = -INFINITY;
#pragma unroll
        for (int js = 0; js < 4; ++js)
#pragma unroll
            for (int r = 0; r < 4; ++r) tmax = fmaxf(tmax, sacc[js][r]);
        tmax = fmaxf(tmax, __shfl_xor(tmax, 16));
        tmax = fmaxf(tmax, __shfl_xor(tmax, 32));
        const float mnew = fmaxf(mrun, tmax);
        const float scl = __expf(mrun - mnew);   // 0 on first tile
        float rs = 0.0f;
#pragma unroll
        for (int js = 0; js < 4; ++js)
#pragma unroll
            for (int r = 0; r < 4; ++r) {
                float p = __expf(sacc[js][r] - mnew);
                sacc[js][r] = p;
                rs += p;
            }
        rs += __shfl_xor(rs, 16);
        rs += __shfl_xor(rs, 32);
        lrun = lrun * scl + rs;
        mrun = mnew;

        // rescale O (R5-verified): oacc row t_local = quad*4+r
        float sclr[4];
#pragma unroll
        for (int r = 0; r < 4; ++r) sclr[r] = __shfl(scl, quad * 4 + r);
#pragma unroll
        for (int jd = 0; jd < 4; ++jd)
#pragma unroll
            for (int r = 0; r < 4; ++r) oacc[jd][r] *= sclr[r];

        // P store [t][s] bf16 into wave-private Ps rows (no barrier needed)
#pragma unroll
        for (int js = 0; js < 4; ++js) {
            unsigned p01 = (unsigned)f2bf(sacc[js][0]) | ((unsigned)f2bf(sacc[js][1]) << 16);
            unsigned p23 = (unsigned)f2bf(sacc[js][2]) | ((unsigned)f2bf(sacc[js][3]) << 16);
            *(uint2*)(Ps + myrow + js * 16 + quad * 4) = make_uint2(p01, p23);
        }
        // in-wave lgkmcnt orders Ps write -> Ps read (same LDS object, aliasing)

        // O += P.V : A=P (m=t, wave-own rows), B=V (n=d)
#pragma unroll
        for (int ks = 0; ks < 2; ++ks) {
            s8v ap = *(const s8v*)(Ps + myrow + ks * 32 + quad * 8);
#pragma unroll
            for (int jd = 0; jd < 4; ++jd) {
                s8v vf = *(const s8v*)(Vs + (jd * 16 + col16) * PT + ks * 32 + quad * 8);
                oacc[jd] = __builtin_amdgcn_mfma_f32_16x16x32_bf16(ap, vf, oacc[jd], 0, 0, 0);
            }
        }
    }

    // epilogue (R5-verified): normalize and write bf16
    const float inv = 1.0f / lrun;
    float invr[4];
#pragma unroll
    for (int r = 0; r < 4; ++r) invr[r] = __shfl(inv, quad * 4 + r);
#pragma unroll
    for (int r = 0; r < 4; ++r) {
        const int t = t0 + w * 16 + quad * 4 + r;
#pragma unroll
        for (int jd = 0; jd < 4; ++jd)
            O[(size_t)(b_ * TT + t) * EE + h * HDIM + jd * 16 + col16] =
                f2bf(oacc[jd][r] * invr[r]);
    }
}

// ---------------------------------------------------------------------------
extern "C" void kernel_launch(void* const* d_in, const int* in_sizes, int n_in,
                              void* d_out, int out_size, void* d_ws, size_t ws_size,
                              hipStream_t stream)
{
    (void)in_sizes; (void)n_in; (void)out_size; (void)ws_size;

    const float* x    = (const float*)d_in[0];
    const float* mask = (const float*)d_in[1];
    const float* Wq   = (const float*)d_in[2];
    const float* bq   = (const float*)d_in[3];
    const float* Wk   = (const float*)d_in[4];
    const float* bk   = (const float*)d_in[5];
    const float* Wv   = (const float*)d_in[6];
    const float* bv   = (const float*)d_in[7];
    const float* Wo   = (const float*)d_in[8];
    const float* bo   = (const float*)d_in[9];
    float* out = (float*)d_out;

    unsigned short* xb  = (unsigned short*)d_ws;
    unsigned short* wqb = xb  + (size_t)MROWS * EE;
    unsigned short* wkb = wqb + (size_t)EE * EE;
    unsigned short* wvb = wkb + (size_t)2 * EE * EE;
    unsigned short* wob = wvb + (size_t)2 * EE * EE;
    unsigned short* mb  = wob + (size_t)EE * EE;
    unsigned short* qp  = mb  + (size_t)BB * TT * TT;
    unsigned short* kp  = qp  + (size_t)MROWS * EE;
    unsigned short* vt  = kp  + (size_t)BB * HH * SS * HDIM;
    unsigned short* ao  = vt  + (size_t)BB * HH * SS * HDIM;

    dim3 blk(256);

    cvt6_kernel<<<4096, blk, 0, stream>>>(x, Wq, Wk, Wv, Wo, mask,
                                          xb, wqb, wkb, wvb, wob, mb);
    gemm_qkv_kernel<<<dim3(1280), blk, 0, stream>>>(
        xb, wqb, wkb, wvb, bq, bk, bv, qp, kp, vt);
    attn_mfma6_kernel<<<dim3(1024), blk, 0, stream>>>(qp, kp, vt, mb, ao);
    gemm_o64_kernel<<<dim3(64, 8), blk, 0, stream>>>(ao, wob, bo, out);
}